// Round 1
// baseline (150.561 us; speedup 1.0000x reference)
//
#include <hip/hip_runtime.h>

// IoULoss: C=4 classes over 16x1024x1024 preds(float, integer-valued) / labels(int).
// out[c] = 1 - 100*iou_c ; iou_c = inter_c/union_c (or 1 if union==0).
// Strategy: count inter[c], cnt_pred[c], cnt_label[c] (union = cp+cl-inter).
// Memory-bound: 134 MB read -> ~21 us floor at 6.3 TB/s.

#define NCLS 4

__global__ __launch_bounds__(256) void iou_count_kernel(
    const float4* __restrict__ preds,
    const int4*   __restrict__ labels,
    unsigned int* __restrict__ counters,   // [3*NCLS]: inter | cnt_pred | cnt_label
    int n4)
{
    int cnt_i[NCLS] = {0, 0, 0, 0};
    int cnt_p[NCLS] = {0, 0, 0, 0};
    int cnt_l[NCLS] = {0, 0, 0, 0};

    const int tid    = blockIdx.x * blockDim.x + threadIdx.x;
    const int stride = gridDim.x * blockDim.x;

    for (int idx = tid; idx < n4; idx += stride) {
        const float4 p = preds[idx];
        const int4   l = labels[idx];
        const int ip0 = (int)p.x, ip1 = (int)p.y, ip2 = (int)p.z, ip3 = (int)p.w;

#pragma unroll
        for (int c = 0; c < NCLS; ++c) {
            const int pm0 = (ip0 == c), lm0 = (l.x == c);
            const int pm1 = (ip1 == c), lm1 = (l.y == c);
            const int pm2 = (ip2 == c), lm2 = (l.z == c);
            const int pm3 = (ip3 == c), lm3 = (l.w == c);
            cnt_i[c] += (pm0 & lm0) + (pm1 & lm1) + (pm2 & lm2) + (pm3 & lm3);
            cnt_p[c] += pm0 + pm1 + pm2 + pm3;
            cnt_l[c] += lm0 + lm1 + lm2 + lm3;
        }
    }

    // Wave (64-lane) shuffle reduction.
#pragma unroll
    for (int c = 0; c < NCLS; ++c) {
#pragma unroll
        for (int off = 32; off > 0; off >>= 1) {
            cnt_i[c] += __shfl_down(cnt_i[c], off);
            cnt_p[c] += __shfl_down(cnt_p[c], off);
            cnt_l[c] += __shfl_down(cnt_l[c], off);
        }
    }

    // Block-level accumulate in LDS, then one atomic per counter per block.
    __shared__ unsigned int s[3 * NCLS];
    if (threadIdx.x < 3 * NCLS) s[threadIdx.x] = 0u;
    __syncthreads();

    if ((threadIdx.x & 63) == 0) {
#pragma unroll
        for (int c = 0; c < NCLS; ++c) {
            atomicAdd(&s[c],            (unsigned int)cnt_i[c]);
            atomicAdd(&s[NCLS + c],     (unsigned int)cnt_p[c]);
            atomicAdd(&s[2 * NCLS + c], (unsigned int)cnt_l[c]);
        }
    }
    __syncthreads();

    if (threadIdx.x < 3 * NCLS)
        atomicAdd(&counters[threadIdx.x], s[threadIdx.x]);
}

__global__ void iou_finalize_kernel(const unsigned int* __restrict__ counters,
                                    float* __restrict__ out)
{
    const int c = threadIdx.x;
    if (c < NCLS) {
        const float inter = (float)counters[c];
        const float uni   = (float)(counters[NCLS + c] + counters[2 * NCLS + c]
                                    - counters[c]);
        const float iou   = (uni == 0.0f) ? 1.0f : (inter / uni);
        out[c] = 1.0f - 100.0f * iou;
    }
}

extern "C" void kernel_launch(void* const* d_in, const int* in_sizes, int n_in,
                              void* d_out, int out_size, void* d_ws, size_t ws_size,
                              hipStream_t stream) {
    const float4* preds  = (const float4*)d_in[0];
    const int4*   labels = (const int4*)d_in[1];
    unsigned int* counters = (unsigned int*)d_ws;
    float* out = (float*)d_out;

    const int n  = in_sizes[0];      // 16*1024*1024
    const int n4 = n / 4;

    // ws is poisoned 0xAA before every call — zero the counter block.
    hipMemsetAsync(counters, 0, 3 * NCLS * sizeof(unsigned int), stream);

    const int threads = 256;
    const int blocks  = 1024;        // 4 blocks/CU; 16 float4-iters per thread
    iou_count_kernel<<<blocks, threads, 0, stream>>>(preds, labels, counters, n4);
    iou_finalize_kernel<<<1, 64, 0, stream>>>(counters, out);
}